// Round 2
// 471.985 us; speedup vs baseline: 1.0657x; 1.0657x over previous
//
#include <hip/hip_runtime.h>

#define S 4096
#define C 2048
#define H 16
#define D 128
#define EPS 1.1920929e-07f
// 1/sqrt(128) * log2(e): fold both attention scale and exp->exp2 base change into q
#define QSCALE (0.08838834764831845f * 1.4426950408889634f)

typedef __attribute__((ext_vector_type(8))) short short8;            // 8 bf16 (MFMA x32 A/B)
typedef __attribute__((ext_vector_type(4))) float f32x4;             // MFMA C/D
typedef __attribute__((ext_vector_type(4))) unsigned int uint4v;

#if __has_builtin(__builtin_amdgcn_exp2f)
#define EXP2F __builtin_amdgcn_exp2f
#else
#define EXP2F exp2f
#endif

__device__ __forceinline__ unsigned short f2bf(float f) {
  unsigned int u = __builtin_bit_cast(unsigned int, f);
  u += 0x7fff + ((u >> 16) & 1);  // RNE
  return (unsigned short)(u >> 16);
}
__device__ __forceinline__ float bf2f(unsigned short v) {
  unsigned int u = ((unsigned int)v) << 16;
  return __builtin_bit_cast(float, u);
}
__device__ __forceinline__ unsigned int pkbf(float a, float b) {
  return (unsigned int)f2bf(a) | ((unsigned int)f2bf(b) << 16);
}
// truncate-pack two fp32 -> bf16 pair in ONE v_perm (no rounding; bias cancelled
// by computing the softmax denominator from these same truncated values)
__device__ __forceinline__ unsigned int pkbf_trunc(float a, float b) {
  return __builtin_amdgcn_perm(__builtin_bit_cast(unsigned int, b),
                               __builtin_bit_cast(unsigned int, a), 0x07060302);
}
__device__ __forceinline__ float lo16f(unsigned int d) {
  return __builtin_bit_cast(float, d << 16);
}
__device__ __forceinline__ float hi16f(unsigned int d) {
  return __builtin_bit_cast(float, d & 0xffff0000u);
}
// async global->LDS, 16B/lane; LDS dest = wave-uniform base + lane*16
__device__ __forceinline__ void gld16(const unsigned short* g, unsigned short* l) {
  __builtin_amdgcn_global_load_lds(
      (const __attribute__((address_space(1))) unsigned int*)g,
      (__attribute__((address_space(3))) unsigned int*)l, 16, 0, 0);
}
// pack 4 dwords (8 bf16) into an MFMA x32 A/B fragment
__device__ __forceinline__ short8 mk_a(unsigned int a, unsigned int b,
                                       unsigned int c, unsigned int d) {
  uint4v u;
  u[0] = a; u[1] = b; u[2] = c; u[3] = d;
  return __builtin_bit_cast(short8, u);
}

// ---------------- fp32 -> bf16 converts ----------------
__global__ void cvt_kernel(const float* __restrict__ src,
                           unsigned short* __restrict__ dst, int n) {
  int i = (blockIdx.x * 256 + threadIdx.x) * 4;
  if (i >= n) return;
  float4 v = *(const float4*)(src + i);
  ushort4 o;
  o.x = f2bf(v.x); o.y = f2bf(v.y); o.z = f2bf(v.z); o.w = f2bf(v.w);
  *(ushort4*)(dst + i) = o;
}
__global__ void cvtw_kernel(const float* __restrict__ w0, const float* __restrict__ w1,
                            const float* __restrict__ w2, const float* __restrict__ w3,
                            unsigned short* __restrict__ dst) {
  const float* srcs[4] = {w0, w1, w2, w3};
  const float* src = srcs[blockIdx.y];
  int i = (blockIdx.x * 256 + threadIdx.x) * 4;
  float4 v = *(const float4*)(src + i);
  ushort4 o;
  o.x = f2bf(v.x); o.y = f2bf(v.y); o.z = f2bf(v.z); o.w = f2bf(v.w);
  *(ushort4*)(dst + (size_t)blockIdx.y * C * C + i) = o;
}
__global__ void bias_concat(const float* __restrict__ bq, const float* __restrict__ bk,
                            const float* __restrict__ bv, float* __restrict__ dst) {
  int i = blockIdx.x * 256 + threadIdx.x;  // 0..6143
  const float* s = (i < C) ? bq : ((i < 2 * C) ? bk : bv);
  dst[i] = s[i & (C - 1)];
}

// ---------------- bf16 GEMM: out[m][n] = sum_k A[m][k]*B[n][k] + bias[n]
// mode 0: fp32 out [M][N] direct.
// mode 1 (QKV, N=6144): LDS-bounce epilogue with coalesced 16B stores.
//   gh=n0>>7: gh<16 -> qh[gh][m][d]; gh<32 -> kh[gh-16][m][d]; else vt[gh-32][d][m]
//   (transposed, with m pi-permuted within 32-col windows; see flash PV).
__global__ __launch_bounds__(256) void gemm_bt(const unsigned short* __restrict__ A,
                                               const unsigned short* __restrict__ B,
                                               const float* __restrict__ bias,
                                               float* __restrict__ outf,
                                               unsigned short* __restrict__ qh,
                                               unsigned short* __restrict__ kh,
                                               unsigned short* __restrict__ vt,
                                               int N, int mode) {
  __shared__ __align__(16) unsigned short U[128 * 136];  // main loop uses first 32 KB
  unsigned short* Al = U;             // 128*64
  unsigned short* Bl = U + 128 * 64;  // 128*64
  const int t = threadIdx.x, w = t >> 6, lane = t & 63;
  const int lq = lane & 15, quad = lane >> 4;
  const int wm = w & 1, wn = w >> 1;
  const int m0 = blockIdx.y * 128, n0 = blockIdx.x * 128;
  f32x4 acc[4][4] = {};
  float biasv[4];
#pragma unroll
  for (int nt = 0; nt < 4; nt++) biasv[nt] = bias[n0 + wn * 64 + nt * 16 + lq];
  const int sr = lane >> 3, sg = lane & 7;
  for (int k0 = 0; k0 < C; k0 += 64) {
    __syncthreads();
#pragma unroll
    for (int p = 0; p < 4; p++) {
      int row = w * 32 + p * 8 + sr;
      int c = sg ^ (row & 7);  // swizzle on the global source; LDS dest lane-linear
      gld16(A + (size_t)(m0 + row) * C + k0 + c * 8, &Al[(w * 32 + p * 8) * 64]);
      gld16(B + (size_t)(n0 + row) * C + k0 + c * 8, &Bl[(w * 32 + p * 8) * 64]);
    }
    __syncthreads();
#pragma unroll
    for (int ks = 0; ks < 2; ks++) {
      short8 af[4], bf[4];
#pragma unroll
      for (int mt = 0; mt < 4; mt++) {
        int row = wm * 64 + mt * 16 + lq;
        af[mt] = *(const short8*)&Al[row * 64 + ((ks * 4 + quad) ^ (lq & 7)) * 8];
      }
#pragma unroll
      for (int nt = 0; nt < 4; nt++) {
        int row = wn * 64 + nt * 16 + lq;
        bf[nt] = *(const short8*)&Bl[row * 64 + ((ks * 4 + quad) ^ (lq & 7)) * 8];
      }
#pragma unroll
      for (int mt = 0; mt < 4; mt++)
#pragma unroll
        for (int nt = 0; nt < 4; nt++)
          acc[mt][nt] = __builtin_amdgcn_mfma_f32_16x16x32_bf16(af[mt], bf[nt], acc[mt][nt], 0, 0, 0);
    }
  }

  if (mode == 0) {
#pragma unroll
    for (int mt = 0; mt < 4; mt++)
#pragma unroll
      for (int nt = 0; nt < 4; nt++) {
        int n = n0 + wn * 64 + nt * 16 + lq;
#pragma unroll
        for (int r = 0; r < 4; r++) {
          int m = m0 + wm * 64 + mt * 16 + quad * 4 + r;  // C/D: col=lane&15, row=quad*4+r
          outf[(size_t)m * N + n] = acc[mt][nt][r] + biasv[nt];
        }
      }
    return;
  }

  // ---- mode 1: LDS bounce, coalesced stores ----
  const int gh = n0 >> 7;
  __syncthreads();
  const int rr = t >> 4, ck = t & 15;
  if (gh < 32) {
    // bounce [m][d], stride 136 shorts (16B-aligned rows)
#pragma unroll
    for (int mt = 0; mt < 4; mt++)
#pragma unroll
      for (int nt = 0; nt < 4; nt++) {
        int dloc = wn * 64 + nt * 16 + lq;
#pragma unroll
        for (int r = 0; r < 4; r++)
          U[(wm * 64 + mt * 16 + quad * 4 + r) * 136 + dloc] = f2bf(acc[mt][nt][r] + biasv[nt]);
      }
    __syncthreads();
    unsigned short* dst = ((gh < 16) ? qh : kh) + (size_t)(gh & 15) * S * D;
#pragma unroll
    for (int p = 0; p < 8; p++) {
      int m = p * 16 + rr;
      uint4 vv = *(const uint4*)&U[m * 136 + ck * 8];
      *(uint4*)(dst + (size_t)(m0 + m) * D + ck * 8) = vv;
    }
  } else {
    // v: bounce transposed [d][m], dword-packed writes.
    // m is pi-permuted within each 32-col window so flash PV can consume P's
    // natural QK^T output layout as an x32 MFMA A-fragment:
    //   window position 8*quad + 4*(mt&1) + r  holds physical row 16*(mt&1)+4*quad+r
    #pragma unroll
    for (int mt = 0; mt < 4; mt++)
#pragma unroll
      for (int nt = 0; nt < 4; nt++) {
        int dloc = wn * 64 + nt * 16 + lq;
        int mlocP = wm * 64 + (mt >> 1) * 32 + quad * 8 + (mt & 1) * 4;
        *(unsigned int*)&U[dloc * 136 + mlocP] =
            pkbf(acc[mt][nt][0] + biasv[nt], acc[mt][nt][1] + biasv[nt]);
        *(unsigned int*)&U[dloc * 136 + mlocP + 2] =
            pkbf(acc[mt][nt][2] + biasv[nt], acc[mt][nt][3] + biasv[nt]);
      }
    __syncthreads();
    unsigned short* dst = vt + (size_t)(gh - 32) * D * S;
#pragma unroll
    for (int p = 0; p < 8; p++) {
      int d = p * 16 + rr;
      uint4 vv = *(const uint4*)&U[d * 136 + ck * 8];
      *(uint4*)(dst + (size_t)d * S + m0 + ck * 8) = vv;
    }
  }
}

// ---------------- fused RMSNorm + rotary, in place on [H][S][D]; y=0 -> q, y=1 -> k ----
__global__ __launch_bounds__(256) void rmsrope_kernel(unsigned short* __restrict__ qh,
                                                      unsigned short* __restrict__ kh,
                                                      const float* __restrict__ qn_w,
                                                      const float* __restrict__ kn_w,
                                                      const float* __restrict__ rope) {
  const int which = blockIdx.y;
  unsigned short* io = which ? kh : qh;
  const float* wgt = which ? kn_w : qn_w;
  const float scale = which ? 1.0f : QSCALE;
  int wid = (blockIdx.x * 256 + threadIdx.x) >> 6;  // wave id = h*S + s
  int lane = threadIdx.x & 63;
  int s = wid & (S - 1);
  unsigned short* row = io + (size_t)wid * D;
  unsigned int pr = *(unsigned int*)(row + lane * 2);
  float a = bf2f((unsigned short)(pr & 0xffff));
  float b = bf2f((unsigned short)(pr >> 16));
  float ss = a * a + b * b;
  for (int m = 1; m < 64; m <<= 1) ss += __shfl_xor(ss, m);
  float inv = rsqrtf(ss * (1.0f / 128.0f) + EPS) * scale;
  float2 wv = *(const float2*)(wgt + lane * 2);
  float an = a * inv * wv.x, bn = b * inv * wv.y;
  float4 r = *(const float4*)(rope + (size_t)s * 256 + lane * 4);
  *(unsigned int*)(row + lane * 2) = pkbf(r.x * an + r.y * bn, r.z * an + r.w * bn);
}

// ---------------- flash attention: BM=32/wave (128/block), BN=128 j-tiles.
// No online max: scores are bounded (rmsnormed q,k; |s|max ~ 12 << fp32 exp range),
// so P = exp2(s*log2e) directly (log2e pre-folded into q), denominator from the
// truncated-bf16 P values (bias cancels in P/sum).
// PV runs at the full x32 MFMA rate: V columns are pi-permuted at creation so the
// QK^T C-layout dwords ARE the x32 A-fragment (no cross-lane shuffle, no x16 MFMA).
__global__ __launch_bounds__(256, 2) void flash_kernel(const unsigned short* __restrict__ qh,
                                                       const unsigned short* __restrict__ kh,
                                                       const unsigned short* __restrict__ vt,
                                                       unsigned short* __restrict__ ao) {
  __shared__ __align__(16) unsigned short Klds[128 * 128];  // [j][d], swizzled (32 KB)
  __shared__ __align__(16) unsigned short Vlds[128 * 128];  // [d][j-perm], swizzled (32 KB)
  const int h = blockIdx.y, i0 = blockIdx.x * 128;
  const int t = threadIdx.x, w = t >> 6, lane = t & 63;
  const int lq = lane & 15, quad = lane >> 4;

  // Q as MFMA B-operand: n=lq (q row), k=quad*8+j (d). scale+log2e pre-folded.
  const unsigned short* Qbase = qh + ((size_t)h * S + i0 + w * 32 + lq) * D;
  short8 qfrag[2][4];
#pragma unroll
  for (int qi = 0; qi < 2; qi++)
#pragma unroll
    for (int kt = 0; kt < 4; kt++)
      qfrag[qi][kt] = *(const short8*)(Qbase + (size_t)qi * 16 * D + kt * 32 + quad * 8);

  f32x4 oacc[2][8] = {};
  float lrun[2] = {0.0f, 0.0f};
  const unsigned short* Kbase = kh + (size_t)h * S * D;
  const unsigned short* Vbase = vt + (size_t)h * D * S;

  const int kr = lane >> 4, kg = lane & 15;  // staging: 4 rows/call, 16 groups/row

  for (int j0 = 0; j0 < S; j0 += 128) {
    __syncthreads();
#pragma unroll
    for (int p = 0; p < 8; p++) {
      int krow = w * 32 + p * 4 + kr;
      gld16(Kbase + (size_t)(j0 + krow) * D + (kg ^ (krow & 7)) * 8,
            &Klds[(w * 32 + p * 4) * 128]);
      gld16(Vbase + (size_t)krow * S + j0 + (kg ^ (krow & 7)) * 8,
            &Vlds[(w * 32 + p * 4) * 128]);
    }
    __syncthreads();

    // S^T = K·Q^T : sacc[qi][nt][r] = s*log2e for [q=lq(+16qi)][j = j0+nt*16+quad*4+r]
    f32x4 sacc[2][8] = {};
    __builtin_amdgcn_s_setprio(1);
#pragma unroll
    for (int kt = 0; kt < 4; kt++)
#pragma unroll
      for (int nt = 0; nt < 8; nt++) {
        int row = nt * 16 + lq;
        short8 af = *(const short8*)&Klds[row * 128 + (((kt * 4 + quad) ^ (row & 7)) * 8)];
        sacc[0][nt] = __builtin_amdgcn_mfma_f32_16x16x32_bf16(af, qfrag[0][kt], sacc[0][nt], 0, 0, 0);
        sacc[1][nt] = __builtin_amdgcn_mfma_f32_16x16x32_bf16(af, qfrag[1][kt], sacc[1][nt], 0, 0, 0);
      }
    __builtin_amdgcn_s_setprio(0);

    // softmax numerators: exp2, truncate-pack to bf16, sum the truncated values
    unsigned int pd[2][8][2];
#pragma unroll
    for (int qi = 0; qi < 2; qi++) {
      float rsum = 0.0f;
#pragma unroll
      for (int nt = 0; nt < 8; nt++) {
        float e0 = EXP2F(sacc[qi][nt][0]);
        float e1 = EXP2F(sacc[qi][nt][1]);
        float e2 = EXP2F(sacc[qi][nt][2]);
        float e3 = EXP2F(sacc[qi][nt][3]);
        unsigned int d0 = pkbf_trunc(e0, e1);
        unsigned int d1 = pkbf_trunc(e2, e3);
        pd[qi][nt][0] = d0;
        pd[qi][nt][1] = d1;
        rsum += (lo16f(d0) + hi16f(d0)) + (lo16f(d1) + hi16f(d1));
      }
      lrun[qi] += rsum;
    }

    // O += P·V at full x32 rate. pd dwords hold j = 32*kk + 16*b + 4*quad + r which
    // is exactly ordinal k = 8*quad + 4*b + r of the pi-permuted V columns, so the
    // A-fragment is {pd[2kk][0], pd[2kk][1], pd[2kk+1][0], pd[2kk+1][1]} verbatim.
    __builtin_amdgcn_s_setprio(1);
#pragma unroll
    for (int kk = 0; kk < 4; kk++) {
      short8 a0 = mk_a(pd[0][2 * kk][0], pd[0][2 * kk][1], pd[0][2 * kk + 1][0], pd[0][2 * kk + 1][1]);
      short8 a1 = mk_a(pd[1][2 * kk][0], pd[1][2 * kk][1], pd[1][2 * kk + 1][0], pd[1][2 * kk + 1][1]);
#pragma unroll
      for (int dt = 0; dt < 8; dt++) {
        int row = dt * 16 + lq;
        short8 bf = *(const short8*)&Vlds[row * 128 + (((kk * 4 + quad) ^ (row & 7)) * 8)];
        oacc[0][dt] = __builtin_amdgcn_mfma_f32_16x16x32_bf16(a0, bf, oacc[0][dt], 0, 0, 0);
        oacc[1][dt] = __builtin_amdgcn_mfma_f32_16x16x32_bf16(a1, bf, oacc[1][dt], 0, 0, 0);
      }
    }
    __builtin_amdgcn_s_setprio(0);
  }

  // final: reduce denominators across quads once, divide, store
#pragma unroll
  for (int qi = 0; qi < 2; qi++) {
    lrun[qi] += __shfl_xor(lrun[qi], 16);
    lrun[qi] += __shfl_xor(lrun[qi], 32);
  }
  float il[2][4];
#pragma unroll
  for (int qi = 0; qi < 2; qi++)
#pragma unroll
    for (int r = 0; r < 4; r++) il[qi][r] = 1.0f / __shfl(lrun[qi], quad * 4 + r);
#pragma unroll
  for (int qi = 0; qi < 2; qi++)
#pragma unroll
    for (int dt = 0; dt < 8; dt++)
#pragma unroll
      for (int r = 0; r < 4; r++)
        ao[(size_t)(i0 + w * 32 + qi * 16 + quad * 4 + r) * C + h * 128 + dt * 16 + lq] =
            f2bf(oacc[qi][dt][r] * il[qi][r]);
}

extern "C" void kernel_launch(void* const* d_in, const int* in_sizes, int n_in,
                              void* d_out, int out_size, void* d_ws, size_t ws_size,
                              hipStream_t stream) {
  const float* x    = (const float*)d_in[0];
  const float* rope = (const float*)d_in[1];
  const float* Wq   = (const float*)d_in[2];
  const float* bq   = (const float*)d_in[3];
  const float* Wk   = (const float*)d_in[4];
  const float* bk   = (const float*)d_in[5];
  const float* Wv   = (const float*)d_in[6];
  const float* bv   = (const float*)d_in[7];
  const float* qn_w = (const float*)d_in[8];
  const float* kn_w = (const float*)d_in[9];
  const float* Wo   = (const float*)d_in[10];
  const float* bo   = (const float*)d_in[11];
  float* out = (float*)d_out;

  unsigned short* xb  = (unsigned short*)d_ws;      // S*C
  unsigned short* wqb = xb + (size_t)S * C;         // 4*C*C (Wq,Wk,Wv,Wo contiguous)
  unsigned short* wob = wqb + (size_t)3 * C * C;
  unsigned short* qh  = wqb + (size_t)4 * C * C;    // [H][S][D]
  unsigned short* kh  = qh + (size_t)S * C;         // [H][S][D]
  unsigned short* vt  = kh + (size_t)S * C;         // [H][D][S] (transposed, pi-permuted)
  unsigned short* ao  = vt + (size_t)S * C;         // [S][C]
  float* bqkv = (float*)(ao + (size_t)S * C);       // 6144 floats

  cvt_kernel<<<S * C / 1024, 256, 0, stream>>>(x, xb, S * C);
  cvtw_kernel<<<dim3(C * C / 1024, 4), 256, 0, stream>>>(Wq, Wk, Wv, Wo, wqb);
  bias_concat<<<3 * C / 256, 256, 0, stream>>>(bq, bk, bv, bqkv);

  // fused QKV projection; epilogue writes q/k head-major and v directly transposed
  gemm_bt<<<dim3(3 * C / 128, S / 128), 256, 0, stream>>>(
      xb, wqb, bqkv, nullptr, qh, kh, vt, 3 * C, 1);

  rmsrope_kernel<<<dim3((H * S) / 4, 2), 256, 0, stream>>>(qh, kh, qn_w, kn_w, rope);

  flash_kernel<<<dim3(S / 128, H), 256, 0, stream>>>(qh, kh, vt, ao);

  gemm_bt<<<dim3(C / 128, S / 128), 256, 0, stream>>>(
      ao, wob, bo, out, nullptr, nullptr, nullptr, C, 0);
}

// Round 3
// 463.617 us; speedup vs baseline: 1.0849x; 1.0180x over previous
//
#include <hip/hip_runtime.h>

#define S 4096
#define C 2048
#define H 16
#define D 128
#define EPS 1.1920929e-07f
// 1/sqrt(128) * log2(e): fold both attention scale and exp->exp2 base change into q
#define QSCALE (0.08838834764831845f * 1.4426950408889634f)
// flash j-tile (double-buffered)
#define BN 64
#define NT (S / BN)

typedef __attribute__((ext_vector_type(8))) short short8;            // 8 bf16 (MFMA x32 A/B)
typedef __attribute__((ext_vector_type(4))) float f32x4;             // MFMA C/D
typedef __attribute__((ext_vector_type(4))) unsigned int uint4v;

#if __has_builtin(__builtin_amdgcn_exp2f)
#define EXP2F __builtin_amdgcn_exp2f
#else
#define EXP2F exp2f
#endif

__device__ __forceinline__ unsigned short f2bf(float f) {
  unsigned int u = __builtin_bit_cast(unsigned int, f);
  u += 0x7fff + ((u >> 16) & 1);  // RNE
  return (unsigned short)(u >> 16);
}
__device__ __forceinline__ float bf2f(unsigned short v) {
  unsigned int u = ((unsigned int)v) << 16;
  return __builtin_bit_cast(float, u);
}
__device__ __forceinline__ unsigned int pkbf(float a, float b) {
  return (unsigned int)f2bf(a) | ((unsigned int)f2bf(b) << 16);
}
// truncate-pack two fp32 -> bf16 pair in ONE v_perm (no rounding; bias cancelled
// by computing the softmax denominator from these same truncated values)
__device__ __forceinline__ unsigned int pkbf_trunc(float a, float b) {
  return __builtin_amdgcn_perm(__builtin_bit_cast(unsigned int, b),
                               __builtin_bit_cast(unsigned int, a), 0x07060302);
}
// async global->LDS, 16B/lane; LDS dest = wave-uniform base + lane*16
__device__ __forceinline__ void gld16(const unsigned short* g, unsigned short* l) {
  __builtin_amdgcn_global_load_lds(
      (const __attribute__((address_space(1))) unsigned int*)g,
      (__attribute__((address_space(3))) unsigned int*)l, 16, 0, 0);
}
// pack 4 dwords (8 bf16) into an MFMA x32 A/B fragment
__device__ __forceinline__ short8 mk_a(unsigned int a, unsigned int b,
                                       unsigned int c, unsigned int d) {
  uint4v u;
  u[0] = a; u[1] = b; u[2] = c; u[3] = d;
  return __builtin_bit_cast(short8, u);
}

// ---------------- fp32 -> bf16 converts ----------------
__global__ void cvt_kernel(const float* __restrict__ src,
                           unsigned short* __restrict__ dst, int n) {
  int i = (blockIdx.x * 256 + threadIdx.x) * 4;
  if (i >= n) return;
  float4 v = *(const float4*)(src + i);
  ushort4 o;
  o.x = f2bf(v.x); o.y = f2bf(v.y); o.z = f2bf(v.z); o.w = f2bf(v.w);
  *(ushort4*)(dst + i) = o;
}
__global__ void cvtw_kernel(const float* __restrict__ w0, const float* __restrict__ w1,
                            const float* __restrict__ w2, const float* __restrict__ w3,
                            unsigned short* __restrict__ dst) {
  const float* srcs[4] = {w0, w1, w2, w3};
  const float* src = srcs[blockIdx.y];
  int i = (blockIdx.x * 256 + threadIdx.x) * 4;
  float4 v = *(const float4*)(src + i);
  ushort4 o;
  o.x = f2bf(v.x); o.y = f2bf(v.y); o.z = f2bf(v.z); o.w = f2bf(v.w);
  *(ushort4*)(dst + (size_t)blockIdx.y * C * C + i) = o;
}
__global__ void bias_concat(const float* __restrict__ bq, const float* __restrict__ bk,
                            const float* __restrict__ bv, float* __restrict__ dst) {
  int i = blockIdx.x * 256 + threadIdx.x;  // 0..6143
  const float* s = (i < C) ? bq : ((i < 2 * C) ? bk : bv);
  dst[i] = s[i & (C - 1)];
}

// ---------------- bf16 GEMM: out[m][n] = sum_k A[m][k]*B[n][k] + bias[n]
// mode 0: fp32 out [M][N] direct.
// mode 1 (QKV, N=6144): LDS-bounce epilogue with coalesced 16B stores.
//   gh=n0>>7: gh<16 -> qh[gh][m][d]; gh<32 -> kh[gh-16][m][d]; else vt[gh-32][d][m]
//   (transposed, with m pi-permuted within 32-col windows; see flash PV).
__global__ __launch_bounds__(256) void gemm_bt(const unsigned short* __restrict__ A,
                                               const unsigned short* __restrict__ B,
                                               const float* __restrict__ bias,
                                               float* __restrict__ outf,
                                               unsigned short* __restrict__ qh,
                                               unsigned short* __restrict__ kh,
                                               unsigned short* __restrict__ vt,
                                               int N, int mode) {
  __shared__ __align__(16) unsigned short U[128 * 136];  // main loop uses first 32 KB
  unsigned short* Al = U;             // 128*64
  unsigned short* Bl = U + 128 * 64;  // 128*64
  const int t = threadIdx.x, w = t >> 6, lane = t & 63;
  const int lq = lane & 15, quad = lane >> 4;
  const int wm = w & 1, wn = w >> 1;
  const int m0 = blockIdx.y * 128, n0 = blockIdx.x * 128;
  f32x4 acc[4][4] = {};
  float biasv[4];
#pragma unroll
  for (int nt = 0; nt < 4; nt++) biasv[nt] = bias[n0 + wn * 64 + nt * 16 + lq];
  const int sr = lane >> 3, sg = lane & 7;
  for (int k0 = 0; k0 < C; k0 += 64) {
    __syncthreads();
#pragma unroll
    for (int p = 0; p < 4; p++) {
      int row = w * 32 + p * 8 + sr;
      int c = sg ^ (row & 7);  // swizzle on the global source; LDS dest lane-linear
      gld16(A + (size_t)(m0 + row) * C + k0 + c * 8, &Al[(w * 32 + p * 8) * 64]);
      gld16(B + (size_t)(n0 + row) * C + k0 + c * 8, &Bl[(w * 32 + p * 8) * 64]);
    }
    __syncthreads();
#pragma unroll
    for (int ks = 0; ks < 2; ks++) {
      short8 af[4], bf[4];
#pragma unroll
      for (int mt = 0; mt < 4; mt++) {
        int row = wm * 64 + mt * 16 + lq;
        af[mt] = *(const short8*)&Al[row * 64 + ((ks * 4 + quad) ^ (lq & 7)) * 8];
      }
#pragma unroll
      for (int nt = 0; nt < 4; nt++) {
        int row = wn * 64 + nt * 16 + lq;
        bf[nt] = *(const short8*)&Bl[row * 64 + ((ks * 4 + quad) ^ (lq & 7)) * 8];
      }
#pragma unroll
      for (int mt = 0; mt < 4; mt++)
#pragma unroll
        for (int nt = 0; nt < 4; nt++)
          acc[mt][nt] = __builtin_amdgcn_mfma_f32_16x16x32_bf16(af[mt], bf[nt], acc[mt][nt], 0, 0, 0);
    }
  }

  if (mode == 0) {
#pragma unroll
    for (int mt = 0; mt < 4; mt++)
#pragma unroll
      for (int nt = 0; nt < 4; nt++) {
        int n = n0 + wn * 64 + nt * 16 + lq;
#pragma unroll
        for (int r = 0; r < 4; r++) {
          int m = m0 + wm * 64 + mt * 16 + quad * 4 + r;  // C/D: col=lane&15, row=quad*4+r
          outf[(size_t)m * N + n] = acc[mt][nt][r] + biasv[nt];
        }
      }
    return;
  }

  // ---- mode 1: LDS bounce, coalesced stores ----
  const int gh = n0 >> 7;
  __syncthreads();
  const int rr = t >> 4, ck = t & 15;
  if (gh < 32) {
    // bounce [m][d], stride 136 shorts (16B-aligned rows)
#pragma unroll
    for (int mt = 0; mt < 4; mt++)
#pragma unroll
      for (int nt = 0; nt < 4; nt++) {
        int dloc = wn * 64 + nt * 16 + lq;
#pragma unroll
        for (int r = 0; r < 4; r++)
          U[(wm * 64 + mt * 16 + quad * 4 + r) * 136 + dloc] = f2bf(acc[mt][nt][r] + biasv[nt]);
      }
    __syncthreads();
    unsigned short* dst = ((gh < 16) ? qh : kh) + (size_t)(gh & 15) * S * D;
#pragma unroll
    for (int p = 0; p < 8; p++) {
      int m = p * 16 + rr;
      uint4 vv = *(const uint4*)&U[m * 136 + ck * 8];
      *(uint4*)(dst + (size_t)(m0 + m) * D + ck * 8) = vv;
    }
  } else {
    // v: bounce transposed [d][m], dword-packed writes.
    // m is pi-permuted within each 32-col window so flash PV can consume P's
    // natural QK^T output layout as an x32 MFMA A-fragment:
    //   window position 8*quad + 4*(mt&1) + r  holds physical row 16*(mt&1)+4*quad+r
    #pragma unroll
    for (int mt = 0; mt < 4; mt++)
#pragma unroll
      for (int nt = 0; nt < 4; nt++) {
        int dloc = wn * 64 + nt * 16 + lq;
        int mlocP = wm * 64 + (mt >> 1) * 32 + quad * 8 + (mt & 1) * 4;
        *(unsigned int*)&U[dloc * 136 + mlocP] =
            pkbf(acc[mt][nt][0] + biasv[nt], acc[mt][nt][1] + biasv[nt]);
        *(unsigned int*)&U[dloc * 136 + mlocP + 2] =
            pkbf(acc[mt][nt][2] + biasv[nt], acc[mt][nt][3] + biasv[nt]);
      }
    __syncthreads();
    unsigned short* dst = vt + (size_t)(gh - 32) * D * S;
#pragma unroll
    for (int p = 0; p < 8; p++) {
      int d = p * 16 + rr;
      uint4 vv = *(const uint4*)&U[d * 136 + ck * 8];
      *(uint4*)(dst + (size_t)d * S + m0 + ck * 8) = vv;
    }
  }
}

// ---------------- fused RMSNorm + rotary, in place on [H][S][D]; y=0 -> q, y=1 -> k ----
__global__ __launch_bounds__(256) void rmsrope_kernel(unsigned short* __restrict__ qh,
                                                      unsigned short* __restrict__ kh,
                                                      const float* __restrict__ qn_w,
                                                      const float* __restrict__ kn_w,
                                                      const float* __restrict__ rope) {
  const int which = blockIdx.y;
  unsigned short* io = which ? kh : qh;
  const float* wgt = which ? kn_w : qn_w;
  const float scale = which ? 1.0f : QSCALE;
  int wid = (blockIdx.x * 256 + threadIdx.x) >> 6;  // wave id = h*S + s
  int lane = threadIdx.x & 63;
  int s = wid & (S - 1);
  unsigned short* row = io + (size_t)wid * D;
  unsigned int pr = *(unsigned int*)(row + lane * 2);
  float a = bf2f((unsigned short)(pr & 0xffff));
  float b = bf2f((unsigned short)(pr >> 16));
  float ss = a * a + b * b;
  for (int m = 1; m < 64; m <<= 1) ss += __shfl_xor(ss, m);
  float inv = rsqrtf(ss * (1.0f / 128.0f) + EPS) * scale;
  float2 wv = *(const float2*)(wgt + lane * 2);
  float an = a * inv * wv.x, bn = b * inv * wv.y;
  float4 r = *(const float4*)(rope + (size_t)s * 256 + lane * 4);
  *(unsigned int*)(row + lane * 2) = pkbf(r.x * an + r.y * bn, r.z * an + r.w * bn);
}

// ---------------- flash attention: BM=32/wave (128/block), BN=64 j-tiles,
// double-buffered K/V staging (prefetch next tile during current compute; the
// implicit vmcnt(0) drain at the per-tile __syncthreads is the only wait, and it
// lands a full compute-phase after issue).
// No online max: scores are bounded (rmsnormed q,k; |s|max ~ 12 << fp32 exp range),
// so P = exp2(s*log2e) directly (log2e pre-folded into q), denominator from the
// truncated-bf16 P values via a ones-column MFMA (bias cancels in P/sum; the
// rowsum lands directly in the oacc C-layout so no epilogue shuffles).
// PV runs at the full x32 MFMA rate: V columns are pi-permuted at creation so the
// QK^T C-layout dwords ARE the x32 A-fragment (no cross-lane shuffle).
__global__ __launch_bounds__(256, 2) void flash_kernel(const unsigned short* __restrict__ qh,
                                                       const unsigned short* __restrict__ kh,
                                                       const unsigned short* __restrict__ vt,
                                                       unsigned short* __restrict__ ao) {
  __shared__ __align__(16) unsigned short Klds[2 * BN * D];  // [buf][j][d], swizzled (2x16 KB)
  __shared__ __align__(16) unsigned short Vlds[2 * D * BN];  // [buf][d][j-perm], swizzled (2x16 KB)
  const int h = blockIdx.y, i0 = blockIdx.x * 128;
  const int t = threadIdx.x, w = t >> 6, lane = t & 63;
  const int lq = lane & 15, quad = lane >> 4;

  // Q as MFMA B-operand: n=lq (q row), k=quad*8+j (d). scale+log2e pre-folded.
  const unsigned short* Qbase = qh + ((size_t)h * S + i0 + w * 32 + lq) * D;
  short8 qfrag[2][4];
#pragma unroll
  for (int qi = 0; qi < 2; qi++)
#pragma unroll
    for (int kt = 0; kt < 4; kt++)
      qfrag[qi][kt] = *(const short8*)(Qbase + (size_t)qi * 16 * D + kt * 32 + quad * 8);

  f32x4 oacc[2][8] = {};
  f32x4 dacc[2] = {};
  const unsigned short* Kbase = kh + (size_t)h * S * D;
  const unsigned short* Vbase = vt + (size_t)h * D * S;

  // staging lane decomposition: K rows are 256B (16 groups of 16B); V rows 128B (8 groups)
  const int k_r = lane >> 4, k_g = lane & 15;
  const int v_r = lane >> 3, v_g = lane & 7;

  uint4v onesu;
  onesu[0] = 0x3F803F80u; onesu[1] = 0x3F803F80u; onesu[2] = 0x3F803F80u; onesu[3] = 0x3F803F80u;
  const short8 ones = __builtin_bit_cast(short8, onesu);

  // prologue: stage tile 0 into buffer 0
#pragma unroll
  for (int p = 0; p < 4; p++) {
    int kr = w * 16 + p * 4 + k_r;
    gld16(Kbase + (size_t)kr * D + (k_g ^ (kr & 7)) * 8, &Klds[(w * 16 + p * 4) * D]);
  }
#pragma unroll
  for (int p = 0; p < 4; p++) {
    int vr = w * 32 + p * 8 + v_r;
    gld16(Vbase + (size_t)vr * S + (v_g ^ (vr & 7)) * 8, &Vlds[(w * 32 + p * 8) * BN]);
  }

  for (int tt = 0; tt < NT; ++tt) {
    const int cur = tt & 1;
    unsigned short* Kc = Klds + cur * (BN * D);
    unsigned short* Vc = Vlds + cur * (D * BN);
    // drain own vmcnt (stage of current buffer complete) + all waves done reading
    // the other buffer -> safe to prefetch into it
    __syncthreads();
    if (tt + 1 < NT) {
      const int j1 = (tt + 1) * BN;
      unsigned short* Kn = Klds + (cur ^ 1) * (BN * D);
      unsigned short* Vn = Vlds + (cur ^ 1) * (D * BN);
#pragma unroll
      for (int p = 0; p < 4; p++) {
        int kr = w * 16 + p * 4 + k_r;
        gld16(Kbase + (size_t)(j1 + kr) * D + (k_g ^ (kr & 7)) * 8, &Kn[(w * 16 + p * 4) * D]);
      }
#pragma unroll
      for (int p = 0; p < 4; p++) {
        int vr = w * 32 + p * 8 + v_r;
        gld16(Vbase + (size_t)vr * S + j1 + (v_g ^ (vr & 7)) * 8, &Vn[(w * 32 + p * 8) * BN]);
      }
    }

    // S^T = K·Q^T : sacc[qi][nt][r] = s*log2e for [q=lq(+16qi)][j = j0+nt*16+quad*4+r]
    f32x4 sacc[2][4] = {};
    __builtin_amdgcn_s_setprio(1);
#pragma unroll
    for (int kt = 0; kt < 4; kt++)
#pragma unroll
      for (int nt = 0; nt < 4; nt++) {
        int row = nt * 16 + lq;
        short8 af = *(const short8*)&Kc[row * D + (((kt * 4 + quad) ^ (row & 7)) * 8)];
        sacc[0][nt] = __builtin_amdgcn_mfma_f32_16x16x32_bf16(af, qfrag[0][kt], sacc[0][nt], 0, 0, 0);
        sacc[1][nt] = __builtin_amdgcn_mfma_f32_16x16x32_bf16(af, qfrag[1][kt], sacc[1][nt], 0, 0, 0);
      }
    __builtin_amdgcn_s_setprio(0);

    // softmax numerators: exp2, truncate-pack to bf16
    unsigned int pd[2][4][2];
#pragma unroll
    for (int qi = 0; qi < 2; qi++)
#pragma unroll
      for (int nt = 0; nt < 4; nt++) {
        float e0 = EXP2F(sacc[qi][nt][0]);
        float e1 = EXP2F(sacc[qi][nt][1]);
        float e2 = EXP2F(sacc[qi][nt][2]);
        float e3 = EXP2F(sacc[qi][nt][3]);
        pd[qi][nt][0] = pkbf_trunc(e0, e1);
        pd[qi][nt][1] = pkbf_trunc(e2, e3);
      }

    // O += P·V at full x32 rate; denominator rows via ones-MFMA on the same A-frags.
    // pd dwords hold j = 32*kk + 16*b + 4*quad + r = ordinal k = 8*quad + 4*b + r of
    // the pi-permuted V columns, so the A-fragment is the pd dwords verbatim.
    __builtin_amdgcn_s_setprio(1);
#pragma unroll
    for (int kk = 0; kk < 2; kk++) {
      short8 a0 = mk_a(pd[0][2 * kk][0], pd[0][2 * kk][1], pd[0][2 * kk + 1][0], pd[0][2 * kk + 1][1]);
      short8 a1 = mk_a(pd[1][2 * kk][0], pd[1][2 * kk][1], pd[1][2 * kk + 1][0], pd[1][2 * kk + 1][1]);
      dacc[0] = __builtin_amdgcn_mfma_f32_16x16x32_bf16(a0, ones, dacc[0], 0, 0, 0);
      dacc[1] = __builtin_amdgcn_mfma_f32_16x16x32_bf16(a1, ones, dacc[1], 0, 0, 0);
#pragma unroll
      for (int dt = 0; dt < 8; dt++) {
        int row = dt * 16 + lq;
        short8 bf = *(const short8*)&Vc[row * BN + (((kk * 4 + quad) ^ (row & 7)) * 8)];
        oacc[0][dt] = __builtin_amdgcn_mfma_f32_16x16x32_bf16(a0, bf, oacc[0][dt], 0, 0, 0);
        oacc[1][dt] = __builtin_amdgcn_mfma_f32_16x16x32_bf16(a1, bf, oacc[1][dt], 0, 0, 0);
      }
    }
    __builtin_amdgcn_s_setprio(0);
  }

  // final: dacc rows are already in oacc C-layout (row = quad*4+r); divide and store
  float il[2][4];
#pragma unroll
  for (int qi = 0; qi < 2; qi++)
#pragma unroll
    for (int r = 0; r < 4; r++) il[qi][r] = 1.0f / dacc[qi][r];
#pragma unroll
  for (int qi = 0; qi < 2; qi++)
#pragma unroll
    for (int dt = 0; dt < 8; dt++)
#pragma unroll
      for (int r = 0; r < 4; r++)
        ao[(size_t)(i0 + w * 32 + qi * 16 + quad * 4 + r) * C + h * 128 + dt * 16 + lq] =
            f2bf(oacc[qi][dt][r] * il[qi][r]);
}

extern "C" void kernel_launch(void* const* d_in, const int* in_sizes, int n_in,
                              void* d_out, int out_size, void* d_ws, size_t ws_size,
                              hipStream_t stream) {
  const float* x    = (const float*)d_in[0];
  const float* rope = (const float*)d_in[1];
  const float* Wq   = (const float*)d_in[2];
  const float* bq   = (const float*)d_in[3];
  const float* Wk   = (const float*)d_in[4];
  const float* bk   = (const float*)d_in[5];
  const float* Wv   = (const float*)d_in[6];
  const float* bv   = (const float*)d_in[7];
  const float* qn_w = (const float*)d_in[8];
  const float* kn_w = (const float*)d_in[9];
  const float* Wo   = (const float*)d_in[10];
  const float* bo   = (const float*)d_in[11];
  float* out = (float*)d_out;

  unsigned short* xb  = (unsigned short*)d_ws;      // S*C
  unsigned short* wqb = xb + (size_t)S * C;         // 4*C*C (Wq,Wk,Wv,Wo contiguous)
  unsigned short* wob = wqb + (size_t)3 * C * C;
  unsigned short* qh  = wqb + (size_t)4 * C * C;    // [H][S][D]
  unsigned short* kh  = qh + (size_t)S * C;         // [H][S][D]
  unsigned short* vt  = kh + (size_t)S * C;         // [H][D][S] (transposed, pi-permuted)
  unsigned short* ao  = vt + (size_t)S * C;         // [S][C]
  float* bqkv = (float*)(ao + (size_t)S * C);       // 6144 floats

  cvt_kernel<<<S * C / 1024, 256, 0, stream>>>(x, xb, S * C);
  cvtw_kernel<<<dim3(C * C / 1024, 4), 256, 0, stream>>>(Wq, Wk, Wv, Wo, wqb);
  bias_concat<<<3 * C / 256, 256, 0, stream>>>(bq, bk, bv, bqkv);

  // fused QKV projection; epilogue writes q/k head-major and v directly transposed
  gemm_bt<<<dim3(3 * C / 128, S / 128), 256, 0, stream>>>(
      xb, wqb, bqkv, nullptr, qh, kh, vt, 3 * C, 1);

  rmsrope_kernel<<<dim3((H * S) / 4, 2), 256, 0, stream>>>(qh, kh, qn_w, kn_w, rope);

  flash_kernel<<<dim3(S / 128, H), 256, 0, stream>>>(qh, kh, vt, ao);

  gemm_bt<<<dim3(C / 128, S / 128), 256, 0, stream>>>(
      ao, wob, bo, out, nullptr, nullptr, nullptr, C, 0);
}

// Round 4
// 439.913 us; speedup vs baseline: 1.1434x; 1.0539x over previous
//
#include <hip/hip_runtime.h>

#define S 4096
#define C 2048
#define H 16
#define D 128
#define EPS 1.1920929e-07f
// 1/sqrt(128) * log2(e): fold both attention scale and exp->exp2 base change into q
#define QSCALE (0.08838834764831845f * 1.4426950408889634f)
// flash j-tile (double-buffered)
#define BN 64
#define NT (S / BN)
// gemm tile
#define GBM 256
#define GBN 128
#define GBK 64
#define NKT (C / GBK)
#define GBUF (GBM * GBK + GBN * GBK)  // shorts per K-tile buffer (24576)

typedef __attribute__((ext_vector_type(8))) short short8;            // 8 bf16 (MFMA x32 A/B)
typedef __attribute__((ext_vector_type(4))) float f32x4;             // MFMA C/D
typedef __attribute__((ext_vector_type(4))) unsigned int uint4v;

#if __has_builtin(__builtin_amdgcn_exp2f)
#define EXP2F __builtin_amdgcn_exp2f
#else
#define EXP2F exp2f
#endif

__device__ __forceinline__ unsigned short f2bf(float f) {
  unsigned int u = __builtin_bit_cast(unsigned int, f);
  u += 0x7fff + ((u >> 16) & 1);  // RNE
  return (unsigned short)(u >> 16);
}
__device__ __forceinline__ float bf2f(unsigned short v) {
  unsigned int u = ((unsigned int)v) << 16;
  return __builtin_bit_cast(float, u);
}
__device__ __forceinline__ unsigned int pkbf(float a, float b) {
  return (unsigned int)f2bf(a) | ((unsigned int)f2bf(b) << 16);
}
// truncate-pack two fp32 -> bf16 pair in ONE v_perm (no rounding; bias cancelled
// by computing the softmax denominator from these same truncated values)
__device__ __forceinline__ unsigned int pkbf_trunc(float a, float b) {
  return __builtin_amdgcn_perm(__builtin_bit_cast(unsigned int, b),
                               __builtin_bit_cast(unsigned int, a), 0x07060302);
}
// async global->LDS, 16B/lane; LDS dest = wave-uniform base + lane*16
__device__ __forceinline__ void gld16(const unsigned short* g, unsigned short* l) {
  __builtin_amdgcn_global_load_lds(
      (const __attribute__((address_space(1))) unsigned int*)g,
      (__attribute__((address_space(3))) unsigned int*)l, 16, 0, 0);
}
// pack 4 dwords (8 bf16) into an MFMA x32 A/B fragment
__device__ __forceinline__ short8 mk_a(unsigned int a, unsigned int b,
                                       unsigned int c, unsigned int d) {
  uint4v u;
  u[0] = a; u[1] = b; u[2] = c; u[3] = d;
  return __builtin_bit_cast(short8, u);
}

// ---------------- fp32 -> bf16 converts ----------------
__global__ void cvt_kernel(const float* __restrict__ src,
                           unsigned short* __restrict__ dst, int n) {
  int i = (blockIdx.x * 256 + threadIdx.x) * 4;
  if (i >= n) return;
  float4 v = *(const float4*)(src + i);
  ushort4 o;
  o.x = f2bf(v.x); o.y = f2bf(v.y); o.z = f2bf(v.z); o.w = f2bf(v.w);
  *(ushort4*)(dst + i) = o;
}
__global__ void cvtw_kernel(const float* __restrict__ w0, const float* __restrict__ w1,
                            const float* __restrict__ w2, const float* __restrict__ w3,
                            unsigned short* __restrict__ dst) {
  const float* srcs[4] = {w0, w1, w2, w3};
  const float* src = srcs[blockIdx.y];
  int i = (blockIdx.x * 256 + threadIdx.x) * 4;
  float4 v = *(const float4*)(src + i);
  ushort4 o;
  o.x = f2bf(v.x); o.y = f2bf(v.y); o.z = f2bf(v.z); o.w = f2bf(v.w);
  *(ushort4*)(dst + (size_t)blockIdx.y * C * C + i) = o;
}
__global__ void bias_concat(const float* __restrict__ bq, const float* __restrict__ bk,
                            const float* __restrict__ bv, float* __restrict__ dst) {
  int i = blockIdx.x * 256 + threadIdx.x;  // 0..6143
  const float* s = (i < C) ? bq : ((i < 2 * C) ? bk : bv);
  dst[i] = s[i & (C - 1)];
}

// ---------------- bf16 GEMM: out[m][n] = sum_k A[m][k]*B[n][k] + bias[n]
// 256x128 block tile, BK=64, 512 threads = 8 waves (4M x 2N, 64x64 per wave).
// 3 LDS buffers, counted-vmcnt pipeline: per K-tile {vmcnt(6); barrier;
// stage(t+2); ds_read+MFMA}. Each wave's vmcnt(6) retires its own 6 oldest
// loads (= tile t); the barrier then publishes every wave's tile-t writes.
// vmcnt never drains to 0 in steady state (T3/T4).
// mode 0: fp32 out [M][N] direct.
// mode 1 (QKV, N=6144): LDS-bounce epilogue with coalesced 16B stores.
//   gh=n0>>7: gh<16 -> qh[gh][m][d]; gh<32 -> kh[gh-16][m][d]; else vt[gh-32][d][m]
//   (transposed, with m pi-permuted within 32-col windows; see flash PV).
__global__ __launch_bounds__(512, 2) void gemm_bt(const unsigned short* __restrict__ A,
                                                  const unsigned short* __restrict__ B,
                                                  const float* __restrict__ bias,
                                                  float* __restrict__ outf,
                                                  unsigned short* __restrict__ qh,
                                                  unsigned short* __restrict__ kh,
                                                  unsigned short* __restrict__ vt,
                                                  int N, int mode) {
  __shared__ __align__(16) unsigned short L[3 * GBUF];  // 144 KB
  const int t = threadIdx.x, w = t >> 6, lane = t & 63;
  const int lq = lane & 15, quad = lane >> 4;
  const int wm = w >> 1, wn = w & 1;  // 4M x 2N

  // XCD-aware bijective swizzle (nwg % 8 == 0 for both grids); bx-major chunks
  // so each XCD's contiguous chunk shares a few B panels (L2 reuse).
  const int nwg = gridDim.x * gridDim.y;
  int id = blockIdx.x * gridDim.y + blockIdx.y;
  int nid = (id & 7) * (nwg >> 3) + (id >> 3);
  const int bx = nid / (int)gridDim.y, by = nid % (int)gridDim.y;
  const int m0 = by * GBM, n0 = bx * GBN;

  f32x4 acc[4][4] = {};
  float biasv[4];
#pragma unroll
  for (int nt = 0; nt < 4; nt++) biasv[nt] = bias[n0 + wn * 64 + nt * 16 + lq];

  // staging: per call one wave covers 8 rows x 8 groups (1 KB); 4 calls A + 2 calls B
  const int srow = lane >> 3, sg = lane & 7;
  auto stage = [&](int tt, int b) {
    unsigned short* Ab = L + b * GBUF;
    unsigned short* Bb = Ab + GBM * GBK;
    const int k0 = tt * GBK;
#pragma unroll
    for (int p = 0; p < 4; p++) {
      int row = p * 64 + w * 8 + srow;
      int c = sg ^ (row & 7);  // swizzle on the global source; LDS dest lane-linear
      gld16(A + (size_t)(m0 + row) * C + k0 + c * 8, Ab + (p * 64 + w * 8) * GBK);
    }
#pragma unroll
    for (int p = 0; p < 2; p++) {
      int row = p * 64 + w * 8 + srow;
      int c = sg ^ (row & 7);
      gld16(B + (size_t)(n0 + row) * C + k0 + c * 8, Bb + (p * 64 + w * 8) * GBK);
    }
  };

  stage(0, 0);
  stage(1, 1);

  int cb = 0;
  for (int tt = 0; tt < NKT; ++tt) {
    if (tt < NKT - 1)
      asm volatile("s_waitcnt vmcnt(6)" ::: "memory");
    else
      asm volatile("s_waitcnt vmcnt(0)" ::: "memory");
    __builtin_amdgcn_s_barrier();
    asm volatile("" ::: "memory");
    if (tt + 2 < NKT) {
      int sb = cb + 2; if (sb >= 3) sb -= 3;
      stage(tt + 2, sb);
    }
    unsigned short* Ab = L + cb * GBUF;
    unsigned short* Bb = Ab + GBM * GBK;
    short8 af[4][2], bf[4][2];
#pragma unroll
    for (int mt = 0; mt < 4; mt++) {
      int row = wm * 64 + mt * 16 + lq;
#pragma unroll
      for (int ks = 0; ks < 2; ks++)
        af[mt][ks] = *(const short8*)&Ab[row * GBK + (((ks * 4 + quad) ^ (row & 7)) * 8)];
    }
#pragma unroll
    for (int nt = 0; nt < 4; nt++) {
      int row = wn * 64 + nt * 16 + lq;
#pragma unroll
      for (int ks = 0; ks < 2; ks++)
        bf[nt][ks] = *(const short8*)&Bb[row * GBK + (((ks * 4 + quad) ^ (row & 7)) * 8)];
    }
    __builtin_amdgcn_s_setprio(1);
#pragma unroll
    for (int ks = 0; ks < 2; ks++)
#pragma unroll
      for (int mt = 0; mt < 4; mt++)
#pragma unroll
        for (int nt = 0; nt < 4; nt++)
          acc[mt][nt] = __builtin_amdgcn_mfma_f32_16x16x32_bf16(af[mt][ks], bf[nt][ks], acc[mt][nt], 0, 0, 0);
    __builtin_amdgcn_s_setprio(0);
    cb = (cb == 2) ? 0 : cb + 1;
  }

  if (mode == 0) {
#pragma unroll
    for (int mt = 0; mt < 4; mt++)
#pragma unroll
      for (int nt = 0; nt < 4; nt++) {
        int n = n0 + wn * 64 + nt * 16 + lq;
#pragma unroll
        for (int r = 0; r < 4; r++) {
          int m = m0 + wm * 64 + mt * 16 + quad * 4 + r;  // C/D: col=lane&15, row=quad*4+r
          outf[(size_t)m * N + n] = acc[mt][nt][r] + biasv[nt];
        }
      }
    return;
  }

  // ---- mode 1: LDS bounce, coalesced stores ----
  const int gh = bx;  // n0 >> 7
  __syncthreads();
  if (gh < 32) {
    // bounce [m][d], stride 136 shorts (16B-aligned rows): 256x136
    unsigned short* U = L;
#pragma unroll
    for (int mt = 0; mt < 4; mt++)
#pragma unroll
      for (int nt = 0; nt < 4; nt++) {
        int dloc = wn * 64 + nt * 16 + lq;
#pragma unroll
        for (int r = 0; r < 4; r++)
          U[(wm * 64 + mt * 16 + quad * 4 + r) * 136 + dloc] = f2bf(acc[mt][nt][r] + biasv[nt]);
      }
    __syncthreads();
    unsigned short* dst = ((gh < 16) ? qh : kh) + (size_t)(gh & 15) * S * D;
    const int rr = t >> 4, ck = t & 15;
#pragma unroll
    for (int p = 0; p < 8; p++) {
      int m = p * 32 + rr;
      uint4 vv = *(const uint4*)&U[m * 136 + ck * 8];
      *(uint4*)(dst + (size_t)(m0 + m) * D + ck * 8) = vv;
    }
  } else {
    // v: bounce transposed [d][m], dword-packed writes: 128x264.
    // m is pi-permuted within each 32-col window so flash PV can consume P's
    // natural QK^T output layout as an x32 MFMA A-fragment:
    //   window position 8*quad + 4*(mt&1) + r  holds physical row 16*(mt&1)+4*quad+r
    unsigned short* U = L;
#pragma unroll
    for (int mt = 0; mt < 4; mt++)
#pragma unroll
      for (int nt = 0; nt < 4; nt++) {
        int dloc = wn * 64 + nt * 16 + lq;
        int mlocP = wm * 64 + (mt >> 1) * 32 + quad * 8 + (mt & 1) * 4;
        *(unsigned int*)&U[dloc * 264 + mlocP] =
            pkbf(acc[mt][nt][0] + biasv[nt], acc[mt][nt][1] + biasv[nt]);
        *(unsigned int*)&U[dloc * 264 + mlocP + 2] =
            pkbf(acc[mt][nt][2] + biasv[nt], acc[mt][nt][3] + biasv[nt]);
      }
    __syncthreads();
    unsigned short* dst = vt + (size_t)(gh - 32) * D * S;
    const int rr = t >> 5, ck = t & 31;
#pragma unroll
    for (int p = 0; p < 8; p++) {
      int d = p * 16 + rr;
      uint4 vv = *(const uint4*)&U[d * 264 + ck * 8];
      *(uint4*)(dst + (size_t)d * S + m0 + ck * 8) = vv;
    }
  }
}

// ---------------- fused RMSNorm + rotary, in place on [H][S][D]; y=0 -> q, y=1 -> k ----
__global__ __launch_bounds__(256) void rmsrope_kernel(unsigned short* __restrict__ qh,
                                                      unsigned short* __restrict__ kh,
                                                      const float* __restrict__ qn_w,
                                                      const float* __restrict__ kn_w,
                                                      const float* __restrict__ rope) {
  const int which = blockIdx.y;
  unsigned short* io = which ? kh : qh;
  const float* wgt = which ? kn_w : qn_w;
  const float scale = which ? 1.0f : QSCALE;
  int wid = (blockIdx.x * 256 + threadIdx.x) >> 6;  // wave id = h*S + s
  int lane = threadIdx.x & 63;
  int s = wid & (S - 1);
  unsigned short* row = io + (size_t)wid * D;
  unsigned int pr = *(unsigned int*)(row + lane * 2);
  float a = bf2f((unsigned short)(pr & 0xffff));
  float b = bf2f((unsigned short)(pr >> 16));
  float ss = a * a + b * b;
  for (int m = 1; m < 64; m <<= 1) ss += __shfl_xor(ss, m);
  float inv = rsqrtf(ss * (1.0f / 128.0f) + EPS) * scale;
  float2 wv = *(const float2*)(wgt + lane * 2);
  float an = a * inv * wv.x, bn = b * inv * wv.y;
  float4 r = *(const float4*)(rope + (size_t)s * 256 + lane * 4);
  *(unsigned int*)(row + lane * 2) = pkbf(r.x * an + r.y * bn, r.z * an + r.w * bn);
}

// ---------------- flash attention: BM=32/wave (128/block), BN=64 j-tiles,
// double-buffered K/V staging (prefetch next tile during current compute).
// No online max: scores are bounded (rmsnormed q,k), P = exp2(s*log2e) directly,
// denominator via ones-column MFMA on the truncated-bf16 P (bias cancels in P/sum).
// PV at full x32 rate: V columns pi-permuted at creation so QK^T C-layout dwords
// ARE the x32 A-fragment.
__global__ __launch_bounds__(256, 2) void flash_kernel(const unsigned short* __restrict__ qh,
                                                       const unsigned short* __restrict__ kh,
                                                       const unsigned short* __restrict__ vt,
                                                       unsigned short* __restrict__ ao) {
  __shared__ __align__(16) unsigned short Klds[2 * BN * D];  // [buf][j][d], swizzled
  __shared__ __align__(16) unsigned short Vlds[2 * D * BN];  // [buf][d][j-perm], swizzled
  const int h = blockIdx.y, i0 = blockIdx.x * 128;
  const int t = threadIdx.x, w = t >> 6, lane = t & 63;
  const int lq = lane & 15, quad = lane >> 4;

  // Q as MFMA B-operand: n=lq (q row), k=quad*8+j (d). scale+log2e pre-folded.
  const unsigned short* Qbase = qh + ((size_t)h * S + i0 + w * 32 + lq) * D;
  short8 qfrag[2][4];
#pragma unroll
  for (int qi = 0; qi < 2; qi++)
#pragma unroll
    for (int kt = 0; kt < 4; kt++)
      qfrag[qi][kt] = *(const short8*)(Qbase + (size_t)qi * 16 * D + kt * 32 + quad * 8);

  f32x4 oacc[2][8] = {};
  f32x4 dacc[2] = {};
  const unsigned short* Kbase = kh + (size_t)h * S * D;
  const unsigned short* Vbase = vt + (size_t)h * D * S;

  const int k_r = lane >> 4, k_g = lane & 15;
  const int v_r = lane >> 3, v_g = lane & 7;

  uint4v onesu;
  onesu[0] = 0x3F803F80u; onesu[1] = 0x3F803F80u; onesu[2] = 0x3F803F80u; onesu[3] = 0x3F803F80u;
  const short8 ones = __builtin_bit_cast(short8, onesu);

  // prologue: stage tile 0 into buffer 0
#pragma unroll
  for (int p = 0; p < 4; p++) {
    int kr = w * 16 + p * 4 + k_r;
    gld16(Kbase + (size_t)kr * D + (k_g ^ (kr & 7)) * 8, &Klds[(w * 16 + p * 4) * D]);
  }
#pragma unroll
  for (int p = 0; p < 4; p++) {
    int vr = w * 32 + p * 8 + v_r;
    gld16(Vbase + (size_t)vr * S + (v_g ^ (vr & 7)) * 8, &Vlds[(w * 32 + p * 8) * BN]);
  }

  for (int tt = 0; tt < NT; ++tt) {
    const int cur = tt & 1;
    unsigned short* Kc = Klds + cur * (BN * D);
    unsigned short* Vc = Vlds + cur * (D * BN);
    __syncthreads();
    if (tt + 1 < NT) {
      const int j1 = (tt + 1) * BN;
      unsigned short* Kn = Klds + (cur ^ 1) * (BN * D);
      unsigned short* Vn = Vlds + (cur ^ 1) * (D * BN);
#pragma unroll
      for (int p = 0; p < 4; p++) {
        int kr = w * 16 + p * 4 + k_r;
        gld16(Kbase + (size_t)(j1 + kr) * D + (k_g ^ (kr & 7)) * 8, &Kn[(w * 16 + p * 4) * D]);
      }
#pragma unroll
      for (int p = 0; p < 4; p++) {
        int vr = w * 32 + p * 8 + v_r;
        gld16(Vbase + (size_t)vr * S + j1 + (v_g ^ (vr & 7)) * 8, &Vn[(w * 32 + p * 8) * BN]);
      }
    }

    // S^T = K·Q^T
    f32x4 sacc[2][4] = {};
    __builtin_amdgcn_s_setprio(1);
#pragma unroll
    for (int kt = 0; kt < 4; kt++)
#pragma unroll
      for (int nt = 0; nt < 4; nt++) {
        int row = nt * 16 + lq;
        short8 af = *(const short8*)&Kc[row * D + (((kt * 4 + quad) ^ (row & 7)) * 8)];
        sacc[0][nt] = __builtin_amdgcn_mfma_f32_16x16x32_bf16(af, qfrag[0][kt], sacc[0][nt], 0, 0, 0);
        sacc[1][nt] = __builtin_amdgcn_mfma_f32_16x16x32_bf16(af, qfrag[1][kt], sacc[1][nt], 0, 0, 0);
      }
    __builtin_amdgcn_s_setprio(0);

    unsigned int pd[2][4][2];
#pragma unroll
    for (int qi = 0; qi < 2; qi++)
#pragma unroll
      for (int nt = 0; nt < 4; nt++) {
        float e0 = EXP2F(sacc[qi][nt][0]);
        float e1 = EXP2F(sacc[qi][nt][1]);
        float e2 = EXP2F(sacc[qi][nt][2]);
        float e3 = EXP2F(sacc[qi][nt][3]);
        pd[qi][nt][0] = pkbf_trunc(e0, e1);
        pd[qi][nt][1] = pkbf_trunc(e2, e3);
      }

    __builtin_amdgcn_s_setprio(1);
#pragma unroll
    for (int kk = 0; kk < 2; kk++) {
      short8 a0 = mk_a(pd[0][2 * kk][0], pd[0][2 * kk][1], pd[0][2 * kk + 1][0], pd[0][2 * kk + 1][1]);
      short8 a1 = mk_a(pd[1][2 * kk][0], pd[1][2 * kk][1], pd[1][2 * kk + 1][0], pd[1][2 * kk + 1][1]);
      dacc[0] = __builtin_amdgcn_mfma_f32_16x16x32_bf16(a0, ones, dacc[0], 0, 0, 0);
      dacc[1] = __builtin_amdgcn_mfma_f32_16x16x32_bf16(a1, ones, dacc[1], 0, 0, 0);
#pragma unroll
      for (int dt = 0; dt < 8; dt++) {
        int row = dt * 16 + lq;
        short8 bf = *(const short8*)&Vc[row * BN + (((kk * 4 + quad) ^ (row & 7)) * 8)];
        oacc[0][dt] = __builtin_amdgcn_mfma_f32_16x16x32_bf16(a0, bf, oacc[0][dt], 0, 0, 0);
        oacc[1][dt] = __builtin_amdgcn_mfma_f32_16x16x32_bf16(a1, bf, oacc[1][dt], 0, 0, 0);
      }
    }
    __builtin_amdgcn_s_setprio(0);
  }

  float il[2][4];
#pragma unroll
  for (int qi = 0; qi < 2; qi++)
#pragma unroll
    for (int r = 0; r < 4; r++) il[qi][r] = 1.0f / dacc[qi][r];
#pragma unroll
  for (int qi = 0; qi < 2; qi++)
#pragma unroll
    for (int dt = 0; dt < 8; dt++)
#pragma unroll
      for (int r = 0; r < 4; r++)
        ao[(size_t)(i0 + w * 32 + qi * 16 + quad * 4 + r) * C + h * 128 + dt * 16 + lq] =
            f2bf(oacc[qi][dt][r] * il[qi][r]);
}

extern "C" void kernel_launch(void* const* d_in, const int* in_sizes, int n_in,
                              void* d_out, int out_size, void* d_ws, size_t ws_size,
                              hipStream_t stream) {
  const float* x    = (const float*)d_in[0];
  const float* rope = (const float*)d_in[1];
  const float* Wq   = (const float*)d_in[2];
  const float* bq   = (const float*)d_in[3];
  const float* Wk   = (const float*)d_in[4];
  const float* bk   = (const float*)d_in[5];
  const float* Wv   = (const float*)d_in[6];
  const float* bv   = (const float*)d_in[7];
  const float* qn_w = (const float*)d_in[8];
  const float* kn_w = (const float*)d_in[9];
  const float* Wo   = (const float*)d_in[10];
  const float* bo   = (const float*)d_in[11];
  float* out = (float*)d_out;

  unsigned short* xb  = (unsigned short*)d_ws;      // S*C
  unsigned short* wqb = xb + (size_t)S * C;         // 4*C*C (Wq,Wk,Wv,Wo contiguous)
  unsigned short* wob = wqb + (size_t)3 * C * C;
  unsigned short* qh  = wqb + (size_t)4 * C * C;    // [H][S][D]
  unsigned short* kh  = qh + (size_t)S * C;         // [H][S][D]
  unsigned short* vt  = kh + (size_t)S * C;         // [H][D][S] (transposed, pi-permuted)
  unsigned short* ao  = vt + (size_t)S * C;         // [S][C]
  float* bqkv = (float*)(ao + (size_t)S * C);       // 6144 floats

  cvt_kernel<<<S * C / 1024, 256, 0, stream>>>(x, xb, S * C);
  cvtw_kernel<<<dim3(C * C / 1024, 4), 256, 0, stream>>>(Wq, Wk, Wv, Wo, wqb);
  bias_concat<<<3 * C / 256, 256, 0, stream>>>(bq, bk, bv, bqkv);

  // fused QKV projection; epilogue writes q/k head-major and v directly transposed
  gemm_bt<<<dim3(3 * C / GBN, S / GBM), 512, 0, stream>>>(
      xb, wqb, bqkv, nullptr, qh, kh, vt, 3 * C, 1);

  rmsrope_kernel<<<dim3((H * S) / 4, 2), 256, 0, stream>>>(qh, kh, qn_w, kn_w, rope);

  flash_kernel<<<dim3(S / 128, H), 256, 0, stream>>>(qh, kh, vt, ao);

  gemm_bt<<<dim3(C / GBN, S / GBM), 512, 0, stream>>>(
      ao, wob, bo, out, nullptr, nullptr, nullptr, C, 0);
}